// Round 6
// baseline (1635.877 us; speedup 1.0000x reference)
//
#include <hip/hip_runtime.h>
#include <math.h>

// fp32 attention layer via split-bf16 (hi/lo) 3-term MFMA emulation.
// GEMMs: 256x192 schedule over K'=3K=9216 (segment selects plane pair
// AhBh/AhBl/AlBh at stage time). Round-4 lockstep phase structure
// (2 barriers/phase + lgkmcnt(0) + sched_barrier pin + setprio) with ONE
// change: A triple-buffered at distance-2 -> counted vmcnt(4) boundary
// (T4: drained loads are a full tile old; never vmcnt(0) mid-loop).

typedef unsigned int u32;
typedef unsigned short u16;
typedef __attribute__((ext_vector_type(8))) short bf16x8;
typedef __attribute__((ext_vector_type(4))) float f32x4;

#define MFMA(a, b, c) __builtin_amdgcn_mfma_f32_16x16x32_bf16((a), (b), (c), 0, 0, 0)

#define GLDS16(g, l) __builtin_amdgcn_global_load_lds( \
    (const __attribute__((address_space(1))) u32*)(g), \
    (__attribute__((address_space(3))) u32*)(l), 16, 0, 0)

__device__ __forceinline__ u16 f2bf(float f) {
  u32 u = __builtin_bit_cast(u32, f);
  return (u16)((u + 0x7fffu + ((u >> 16) & 1u)) >> 16);  // RNE
}
__device__ __forceinline__ float bf2f(u16 h) {
  u32 u = ((u32)h) << 16;
  return __builtin_bit_cast(float, u);
}
__device__ __forceinline__ void split2(float f, u16& h, u16& l) {
  h = f2bf(f);
  l = f2bf(f - bf2f(h));
}
__device__ __forceinline__ bf16x8 ld16(const u16* p) {
  return *reinterpret_cast<const bf16x8*>(p);
}

// ---------------------------------------------------------------- split ----
__global__ void split_kernel(const float* __restrict__ src, u16* __restrict__ hi,
                             u16* __restrict__ lo, long n) {
  long i = ((long)blockIdx.x * 256 + threadIdx.x) * 4;
  if (i >= n) return;
  const float4 v = *reinterpret_cast<const float4*>(src + i);
  ushort4 h, l;
  split2(v.x, h.x, l.x);
  split2(v.y, h.y, l.y);
  split2(v.z, h.z, l.z);
  split2(v.w, h.w, l.w);
  *reinterpret_cast<ushort4*>(hi + i) = h;
  *reinterpret_cast<ushort4*>(lo + i) = l;
}

// --------------------------------------------------- 256x192 tiled GEMM ----
// C[M,N] = Ah*Bh^T + Ah*Bl^T + Al*Bh^T, planes [rows][3072]. K' = 9216,
// NT=144 K-tiles of 64. 8 waves (2M x 4N), wave tile 128x48.
// LDS: A 3-buf x 256x64 + B 2-buf x 192x64 = 144 KiB, XOR-swizzled
// (storage chunk = chunk ^ (row&7); linear glds dest + pre-swizzled src).
// Tile t reads A[t%3], B[t&1]. Phases (lockstep: RD+stage | bar,lgkm0,
// schedbar | MFMA | bar):
//  ph0: rd Bkh0+A0kh0, stage B(t+1)x3 | 12 MFMA
//  ph1: rd Bkh1+A0kh1, stage A(t+2) j0,j1 | 12 MFMA
//  ph2: rd A1kh0,      stage A(t+2) j2,j3 | 12 MFMA
//  ph3: rd A1kh1 | 12 MFMA | vmcnt(4) | bar
// Boundary FIFO per wave: [A(t+1)x4 | B(t+1)x3 | A(t+2)x4] -> vmcnt(4)
// retires A(t+1)+B(t+1) (issued a full tile ago), keeps A(t+2) in flight.
// MODE 0: write C as hi/lo bf16 planes.  MODE 1: fp32 C + bias[col].
template <int MODE>
__global__ __launch_bounds__(512, 2) void gemm192(
    const u16* __restrict__ Ah, const u16* __restrict__ Al,
    const u16* __restrict__ Bh, const u16* __restrict__ Bl,
    int M, int N,
    u16* __restrict__ Ch, u16* __restrict__ Cl,
    float* __restrict__ Cf, const float* __restrict__ bias) {
  constexpr int NT = 144;
  __shared__ u16 ldsA[3][256 * 64];  // 96 KiB
  __shared__ u16 ldsB[2][192 * 64];  // 48 KiB
  const int tid = threadIdx.x;
  const int lane = tid & 63;
  const int w = tid >> 6;
  const int wr = w >> 2, wc = w & 3;
  const int lr = lane & 15, lg = lane >> 4;

  const int mt = M >> 8;  // 16
  const int nwg = gridDim.x;
  const int bid = blockIdx.x;
  const int wg = (bid & 7) * (nwg >> 3) + (bid >> 3);  // XCD swizzle (nwg%8==0)
  const int bm = wg % mt, bn = wg / mt;

  const int srow = lane >> 3;                    // 0..7
  const int sgc = ((lane & 7) ^ srow) * 8;       // inverse-swizzled global col

  // stage 8KB piece j (A: j=0..3; B: j=0..2) of K-tile kt into buffer buf
  auto stA = [&](int buf, int kt, int j) {
    const int seg = kt / 48;
    const int ko = (kt - seg * 48) * 64;
    const u16* P = (seg < 2) ? Ah : Al;
    const int r = j * 64 + w * 8 + srow;
    GLDS16(P + (long)(bm * 256 + r) * 3072 + ko + sgc,
           &ldsA[buf][(j * 64 + w * 8) * 64]);
  };
  auto stB = [&](int buf, int kt, int j) {
    const int seg = kt / 48;
    const int ko = (kt - seg * 48) * 64;
    const u16* P = (seg == 1) ? Bl : Bh;
    const int r = j * 64 + w * 8 + srow;
    GLDS16(P + (long)(bn * 192 + r) * 3072 + ko + sgc,
           &ldsB[buf][(j * 64 + w * 8) * 64]);
  };

  f32x4 acc[8][3];
#pragma unroll
  for (int m = 0; m < 8; ++m)
#pragma unroll
    for (int n = 0; n < 3; ++n)
#pragma unroll
      for (int j = 0; j < 4; ++j) acc[m][n][j] = 0.f;

  // prologue FIFO: A(0)x4, B(0)x3, A(1)x4 -> vmcnt(4) completes A(0),B(0)
  stA(0, 0, 0); stA(0, 0, 1); stA(0, 0, 2); stA(0, 0, 3);
  stB(0, 0, 0); stB(0, 0, 1); stB(0, 0, 2);
  stA(1, 1, 0); stA(1, 1, 1); stA(1, 1, 2); stA(1, 1, 3);
  asm volatile("s_waitcnt vmcnt(4)" ::: "memory");
  __builtin_amdgcn_s_barrier();

  const int aRow0 = wr * 128 + lr;
  const int bRow0 = wc * 48 + lr;
  const int c0 = (lg ^ (lr & 7)) * 8;  // swizzled chunk addr, K-half 0

#define RD_A(dst, MQ, KH)                                                  \
  _Pragma("unroll") for (int m = 0; m < 4; ++m) dst[m] =                   \
      ld16(&LA[(aRow0 + (MQ)*64 + m * 16) * 64 + (c0 ^ ((KH)*32))]);
#define RD_B(dst, KH)                                                      \
  _Pragma("unroll") for (int n = 0; n < 3; ++n) dst[n] =                   \
      ld16(&LB[(bRow0 + n * 16) * 64 + (c0 ^ ((KH)*32))]);
#define DO_MFMA(a, b, MQ)                                                  \
  __builtin_amdgcn_s_setprio(1);                                           \
  _Pragma("unroll") for (int m = 0; m < 4; ++m)                            \
  _Pragma("unroll") for (int n = 0; n < 3; ++n)                            \
      acc[(MQ)*4 + m][n] = MFMA(a[m], b[n], acc[(MQ)*4 + m][n]);           \
  __builtin_amdgcn_s_setprio(0);
#define PH_SYNC()                                                          \
  __builtin_amdgcn_s_barrier();                                            \
  asm volatile("s_waitcnt lgkmcnt(0)" ::: "memory");                       \
  __builtin_amdgcn_sched_barrier(0);

  int curA = 0;  // t % 3
  for (int t = 0; t < NT; ++t) {
    const u16* LA = ldsA[curA];
    const u16* LB = ldsB[t & 1];
    const int nA = (curA + 2 >= 3) ? curA - 1 : curA + 2;  // (t+2)%3
    bf16x8 a0[4], a1[4], bk0[3], bk1[3];
    // ph0: read B kh0 + A0 kh0; stage B(t+1)
    RD_B(bk0, 0);
    RD_A(a0, 0, 0);
    if (t + 1 < NT) {
      stB((t + 1) & 1, t + 1, 0);
      stB((t + 1) & 1, t + 1, 1);
      stB((t + 1) & 1, t + 1, 2);
    }
    PH_SYNC();
    DO_MFMA(a0, bk0, 0);
    __builtin_amdgcn_s_barrier();
    // ph1: read B kh1 + A0 kh1; stage A(t+2) j0,j1
    RD_B(bk1, 1);
    RD_A(a0, 0, 1);
    if (t + 2 < NT) { stA(nA, t + 2, 0); stA(nA, t + 2, 1); }
    PH_SYNC();
    DO_MFMA(a0, bk1, 0);
    __builtin_amdgcn_s_barrier();
    // ph2: read A1 kh0; stage A(t+2) j2,j3
    RD_A(a1, 1, 0);
    if (t + 2 < NT) { stA(nA, t + 2, 2); stA(nA, t + 2, 3); }
    PH_SYNC();
    DO_MFMA(a1, bk0, 1);
    __builtin_amdgcn_s_barrier();
    // ph3: read A1 kh1; boundary counted wait
    RD_A(a1, 1, 1);
    PH_SYNC();
    DO_MFMA(a1, bk1, 1);
    if (t + 2 < NT)
      asm volatile("s_waitcnt vmcnt(4)" ::: "memory");
    else
      asm volatile("s_waitcnt vmcnt(0)" ::: "memory");
    __builtin_amdgcn_s_barrier();
    curA = (curA + 1 >= 3) ? 0 : curA + 1;
  }
#undef RD_A
#undef RD_B
#undef DO_MFMA
#undef PH_SYNC

  // epilogue: C/D layout col=lane&15, row=(lane>>4)*4+j (m89-verified)
#pragma unroll
  for (int m = 0; m < 8; ++m)
#pragma unroll
    for (int j = 0; j < 4; ++j) {
      const long row = (long)bm * 256 + wr * 128 + m * 16 + lg * 4 + j;
#pragma unroll
      for (int n = 0; n < 3; ++n) {
        const long col = (long)bn * 192 + wc * 48 + n * 16 + lr;
        const long idx = row * N + col;
        const float v = acc[m][n][j];
        if (MODE == 0) {
          u16 h, l;
          split2(v, h, l);
          Ch[idx] = h;
          Cl[idx] = l;
        } else {
          Cf[idx] = v + bias[col];
        }
      }
    }
}

// ---------------------------------------------------------------- pack K ---
__global__ void pack_k(const u16* __restrict__ QKVh, const u16* __restrict__ QKVl,
                       u16* __restrict__ Kp) {
  const int t = blockIdx.x * 256 + threadIdx.x;
  const int lane = t & 63;
  const int rec3 = t >> 6;
  const int c = rec3 % 3;
  const int kb = (rec3 / 3) & 127;
  const int hl = rec3 / 384;
  const int lr = lane & 15, lg = lane >> 4;
  const long src =
      ((long)((hl >> 5) * 2048 + kb * 16 + lr)) * 9216 + 3072 + (hl & 31) * 96 + c * 32 + lg * 8;
  const long dst = ((long)rec3 * 2) * 512 + lane * 8;
  *reinterpret_cast<bf16x8*>(Kp + dst) = ld16(QKVh + src);
  *reinterpret_cast<bf16x8*>(Kp + dst + 512) = ld16(QKVl + src);
}

// ---------------------------------------------------------------- pack V ---
__global__ __launch_bounds__(256) void pack_v(const u16* __restrict__ QKVh,
                                              const u16* __restrict__ QKVl,
                                              u16* __restrict__ Vp) {
  __shared__ u16 sV[2][32 * 96];
  const int tid = threadIdx.x;
  const int hl = blockIdx.x >> 6;
  const int kq = blockIdx.x & 63;
  const long rowbase = ((long)((hl >> 5) * 2048 + kq * 32)) * 9216 + 6144 + (hl & 31) * 96;
#pragma unroll
  for (int i = 0; i < 3; ++i) {
    const int idx = i * 256 + tid;
    const int pl = idx / 384;
    const int r2 = idx % 384;
    const int row = r2 / 12, cu = r2 % 12;
    const u16* srcp = (pl ? QKVl : QKVh) + rowbase + (long)row * 9216 + cu * 8;
    *reinterpret_cast<bf16x8*>(&sV[pl][row * 96 + cu * 8]) = ld16(srcp);
  }
  __syncthreads();
#pragma unroll
  for (int i = 0; i < 3; ++i) {
    const int idx = i * 256 + tid;
    const int lane = idx & 63;
    const int rl = idx >> 6;
    const int n = rl >> 1, pl = rl & 1;
    const int lr = lane & 15, lg = lane >> 4;
    bf16x8 o;
#pragma unroll
    for (int e = 0; e < 8; ++e) o[e] = (short)sV[pl][(lg * 8 + e) * 96 + n * 16 + lr];
    const long dst = ((((long)hl * 6 + n) * 64 + kq) * 2 + pl) * 512 + lane * 8;
    *reinterpret_cast<bf16x8*>(Vp + dst) = o;
  }
}

// ------------------------------------------------------------- attention ---
__global__ __launch_bounds__(256, 2) void attn_kernel(
    const u16* __restrict__ QKVh, const u16* __restrict__ QKVl,
    const u16* __restrict__ Kp, const u16* __restrict__ Vp,
    u16* __restrict__ AOh, u16* __restrict__ AOl) {
  __shared__ u16 kv[2][24 * 512];
  __shared__ u16 pb[4][2][512];
  const int lane = threadIdx.x & 63;
  const int wv = threadIdx.x >> 6;
  const int lr = lane & 15, lg = lane >> 4;

  const int nwg = gridDim.x;
  const int bid = blockIdx.x;
  const int wg = (bid & 7) * (nwg >> 3) + (bid >> 3);
  const int hl = wg >> 5;
  const int qblk = wg & 31;
  const int b = hl >> 5;
  const int q0 = qblk * 64 + wv * 16;

  bf16x8 qh[3], ql[3];
  {
    const long qofs = ((long)(b * 2048 + q0 + lr)) * 9216 + (hl & 31) * 96 + lg * 8;
#pragma unroll
    for (int c = 0; c < 3; ++c) {
      qh[c] = ld16(QKVh + qofs + c * 32);
      ql[c] = ld16(QKVl + qofs + c * 32);
    }
  }

  f32x4 o_acc[6];
#pragma unroll
  for (int n = 0; n < 6; ++n)
#pragma unroll
    for (int j = 0; j < 4; ++j) o_acc[n][j] = 0.f;
  float lsum[4] = {0.f, 0.f, 0.f, 0.f};

  const float scale = 0.10206207261596577f;  // 96^-0.5
  u16* pbh = pb[wv][0];
  u16* pbl = pb[wv][1];

  auto stage = [&](int nb, int it) {
    const long kbase = ((long)hl * 768 + (long)it * 12) * 512;
    const long vbase = ((long)hl * 768 + (long)it * 2) * 512;
#pragma unroll
    for (int j = 0; j < 6; ++j) {
      const int r = wv * 6 + j;
      const u16* src;
      if (r < 12) {
        const int tt = r / 6, rc = r % 6;
        src = Kp + kbase + ((long)(tt * 6 + rc)) * 512 + lane * 8;
      } else {
        const int r2 = r - 12;
        src = Vp + vbase + ((long)((r2 >> 1) * 128 + (r2 & 1))) * 512 + lane * 8;
      }
      GLDS16(src, &kv[nb][r * 512]);
    }
  };

  stage(0, 0);
  __syncthreads();

  for (int it = 0; it < 64; ++it) {
    const int nb = it & 1;
    if (it < 63) stage(nb ^ 1, it + 1);
    const u16* L = kv[nb];

    f32x4 s0, s1;
#pragma unroll
    for (int j = 0; j < 4; ++j) { s0[j] = 0.f; s1[j] = 0.f; }
#pragma unroll
    for (int c = 0; c < 3; ++c) {
      const bf16x8 kh0 = ld16(L + (c * 2 + 0) * 512 + lane * 8);
      const bf16x8 kl0 = ld16(L + (c * 2 + 1) * 512 + lane * 8);
      const bf16x8 kh1 = ld16(L + (6 + c * 2 + 0) * 512 + lane * 8);
      const bf16x8 kl1 = ld16(L + (6 + c * 2 + 1) * 512 + lane * 8);
      s0 = MFMA(qh[c], kh0, s0);
      s1 = MFMA(qh[c], kh1, s1);
      s0 = MFMA(qh[c], kl0, s0);
      s1 = MFMA(qh[c], kl1, s1);
      s0 = MFMA(ql[c], kh0, s0);
      s1 = MFMA(ql[c], kh1, s1);
    }

#pragma unroll
    for (int j = 0; j < 4; ++j) {
      const float p0 = __expf(fmaf(s0[j], scale, -12.f));
      const float p1 = __expf(fmaf(s1[j], scale, -12.f));
      lsum[j] += p0 + p1;
      const int r = lg * 4 + j;
      const int key = j ^ lg;
      u16 h, l;
      split2(p0, h, l);
      const int a0 = r * 32 + ((((lr >> 3) ^ key) & 3) << 3) + (lr & 7);
      pbh[a0] = h;
      pbl[a0] = l;
      split2(p1, h, l);
      const int a1 = r * 32 + ((((2 + (lr >> 3)) ^ key) & 3) << 3) + (lr & 7);
      pbh[a1] = h;
      pbl[a1] = l;
    }
    const int rkey = (lr & 3) ^ (lr >> 2);
    const int ra = lr * 32 + (((lg ^ rkey) & 3) << 3);
    const bf16x8 pah = ld16(&pbh[ra]);
    const bf16x8 pal = ld16(&pbl[ra]);

#pragma unroll
    for (int n = 0; n < 6; ++n) {
      const bf16x8 vh = ld16(L + (12 + n * 2 + 0) * 512 + lane * 8);
      const bf16x8 vl = ld16(L + (12 + n * 2 + 1) * 512 + lane * 8);
      o_acc[n] = MFMA(pah, vh, o_acc[n]);
      o_acc[n] = MFMA(pah, vl, o_acc[n]);
      o_acc[n] = MFMA(pal, vh, o_acc[n]);
    }
    __syncthreads();
  }

  float inv[4];
#pragma unroll
  for (int j = 0; j < 4; ++j) {
    float rs = lsum[j];
#pragma unroll
    for (int mk = 1; mk < 16; mk <<= 1) rs += __shfl_xor(rs, mk);
    inv[j] = 1.f / rs;
  }
#pragma unroll
  for (int n = 0; n < 6; ++n)
#pragma unroll
    for (int j = 0; j < 4; ++j) {
      const long row = (long)(b * 2048 + q0 + lg * 4 + j);
      const long col = (long)(hl & 31) * 96 + n * 16 + lr;
      u16 h, l;
      split2(o_acc[n][j] * inv[j], h, l);
      AOh[row * 3072 + col] = h;
      AOl[row * 3072 + col] = l;
    }
}

// ---------------------------------------------------------------- launch ---
extern "C" void kernel_launch(void* const* d_in, const int* in_sizes, int n_in,
                              void* d_out, int out_size, void* d_ws, size_t ws_size,
                              hipStream_t stream) {
  const float* x = (const float*)d_in[0];     // [4096][3072]
  const float* wqkv = (const float*)d_in[1];  // [9216][3072]
  const float* wo = (const float*)d_in[2];    // [3072][3072]
  const float* bo = (const float*)d_in[3];    // [3072]
  float* out = (float*)d_out;                 // [4096][3072]
  char* ws = (char*)d_ws;

  const size_t E_X = (size_t)4096 * 3072;
  const size_t E_WQ = (size_t)9216 * 3072;
  const size_t E_QKV = (size_t)4096 * 9216;

  u16* XH = (u16*)ws;
  u16* XL = XH + E_X;
  char* W0 = ws + 4 * E_X;
  u16* WQH = (u16*)W0;
  u16* WQL = WQH + E_WQ;
  char* Q0 = W0 + 4 * E_WQ;
  u16* QKVH = (u16*)Q0;
  u16* QKVL = QKVH + E_QKV;
  char* V0 = Q0 + 4 * E_QKV;
  u16* VP = (u16*)V0;
  u16* KP = (u16*)ws;            // reuses X region after GEMM1
  u16* AOH = (u16*)W0;           // reuses WQKV region after GEMM1
  u16* AOL = AOH + E_X;
  u16* WOH = (u16*)(W0 + 4 * E_X);
  u16* WOL = WOH + (size_t)3072 * 3072;

  const size_t need = 4 * (E_X + E_WQ + E_QKV + E_X);
  if (ws_size < need) return;

  split_kernel<<<12288, 256, 0, stream>>>(x, XH, XL, (long)E_X);
  split_kernel<<<27648, 256, 0, stream>>>(wqkv, WQH, WQL, (long)E_WQ);
  gemm192<0><<<768, 512, 0, stream>>>(XH, XL, WQH, WQL, 4096, 9216,
                                      QKVH, QKVL, nullptr, nullptr);
  pack_k<<<6144, 256, 0, stream>>>(QKVH, QKVL, KP);
  pack_v<<<4096, 256, 0, stream>>>(QKVH, QKVL, VP);
  split_kernel<<<9216, 256, 0, stream>>>(wo, WOH, WOL, (long)(3072 * 3072));
  attn_kernel<<<2048, 256, 0, stream>>>(QKVH, QKVL, KP, VP, AOH, AOL);
  gemm192<1><<<256, 512, 0, stream>>>(AOH, AOL, WOH, WOL, 4096, 3072,
                                      nullptr, nullptr, out, bo);
}

// Round 8
// 1303.070 us; speedup vs baseline: 1.2554x; 1.2554x over previous
//
#include <hip/hip_runtime.h>
#include <math.h>

// fp32 attention layer via split-bf16 (hi/lo) 3-term MFMA emulation.
// All matrices stored INTERLEAVED: [row][(col/32)*64 + col%32 + plane*32]
// (hi|lo of each 32-col block adjacent). GEMM: 256x192 tile, BK=32 = one
// 64-elem interleaved block; each staged tile feeds all 3 MFMA terms
// (AhBh+AhBl+AlBh) -> 1.5x less fetch/staging/ds_read than K'=3K form.
// Round-4 lockstep sync (2 phases/tile, bar+lgkm0+schedbar, vmcnt(0)
// drain at tile end - counted vmcnt proved locality-hostile here r5/r6).

typedef unsigned int u32;
typedef unsigned short u16;
typedef __attribute__((ext_vector_type(8))) short bf16x8;
typedef __attribute__((ext_vector_type(4))) float f32x4;

#define MFMA(a, b, c) __builtin_amdgcn_mfma_f32_16x16x32_bf16((a), (b), (c), 0, 0, 0)

#define GLDS16(g, l) __builtin_amdgcn_global_load_lds( \
    (const __attribute__((address_space(1))) u32*)(g), \
    (__attribute__((address_space(3))) u32*)(l), 16, 0, 0)

__device__ __forceinline__ u16 f2bf(float f) {
  u32 u = __builtin_bit_cast(u32, f);
  return (u16)((u + 0x7fffu + ((u >> 16) & 1u)) >> 16);  // RNE
}
__device__ __forceinline__ float bf2f(u16 h) {
  u32 u = ((u32)h) << 16;
  return __builtin_bit_cast(float, u);
}
__device__ __forceinline__ void split2(float f, u16& h, u16& l) {
  h = f2bf(f);
  l = f2bf(f - bf2f(h));
}
__device__ __forceinline__ bf16x8 ld16(const u16* p) {
  return *reinterpret_cast<const bf16x8*>(p);
}

// ---------------------------------------------------------------- split ----
// fp32 [R][3072] -> interleaved hi/lo u16 [R][6144].
__global__ void split_kernel(const float* __restrict__ src, u16* __restrict__ dst,
                             long n) {
  long i = ((long)blockIdx.x * 256 + threadIdx.x) * 4;
  if (i >= n) return;
  const float4 v = *reinterpret_cast<const float4*>(src + i);
  const u32 i32 = (u32)i;
  const u32 row = i32 / 3072u;
  const u32 col = i32 - row * 3072u;
  const long base = (long)row * 6144 + (col >> 5) * 64 + (col & 31);
  ushort4 h, l;
  split2(v.x, h.x, l.x);
  split2(v.y, h.y, l.y);
  split2(v.z, h.z, l.z);
  split2(v.w, h.w, l.w);
  *reinterpret_cast<ushort4*>(dst + base) = h;
  *reinterpret_cast<ushort4*>(dst + base + 32) = l;
}

// ------------------------------------------- 256x192 3-term tiled GEMM ----
// C[M,N] = Ah*Bh^T + Ah*Bl^T + Al*Bh^T; A2[M][6144], B2[N][6144] interleaved.
// K=3072 -> NT=96 tiles of 32 (one 64-elem interleaved block). 8 waves
// (2M x 4N), wave tile 128x48. LDS: 2 dbuf x (A 256x64 + B 192x64) u16
// = 112 KiB, XOR-swizzled (chunk ^= row&7, 8 chunks of 16B per row;
// linear glds dest + pre-swizzled per-lane global src). Per tile:
//  ph0: rd bh/bl(6)+a-half0 hi/lo(8), stage t+1 (A x4 + B x3)
//       | bar,lgkm0,schedbar | 36 MFMA | bar
//  ph1: rd a-half1 hi/lo(8) | bar,lgkm0,schedbar | 36 MFMA | vmcnt(0) | bar
// MODE 0: write C interleaved u16 [M][2N].  MODE 1: fp32 C + bias[col].
template <int MODE>
__global__ __launch_bounds__(512, 2) void gemm3t(
    const u16* __restrict__ A2, const u16* __restrict__ B2,
    int M, int N,
    u16* __restrict__ C2, float* __restrict__ Cf, const float* __restrict__ bias) {
  constexpr int NT = 96;
  __shared__ u16 ldsA[2][256 * 64];  // 64 KiB
  __shared__ u16 ldsB[2][192 * 64];  // 48 KiB
  const int tid = threadIdx.x;
  const int lane = tid & 63;
  const int w = tid >> 6;
  const int wr = w >> 2, wc = w & 3;
  const int lr = lane & 15, lg = lane >> 4;

  const int mt = M >> 8;  // 16
  const int nwg = gridDim.x;
  const int bid = blockIdx.x;
  const int wg = (bid & 7) * (nwg >> 3) + (bid >> 3);  // XCD swizzle (nwg%8==0)
  const int bm = wg % mt, bn = wg / mt;

  const int srow = lane >> 3;               // 0..7
  const int sgc = ((lane & 7) ^ srow) * 8;  // inverse-swizzled src offset

  // stage 8KB piece j of K-tile kt into buffer buf (A: j=0..3, B: j=0..2)
  auto stA = [&](int buf, int kt, int j) {
    const int r = j * 64 + w * 8 + srow;
    GLDS16(A2 + (long)(bm * 256 + r) * 6144 + kt * 64 + sgc,
           &ldsA[buf][(j * 64 + w * 8) * 64]);
  };
  auto stB = [&](int buf, int kt, int j) {
    const int r = j * 64 + w * 8 + srow;
    GLDS16(B2 + (long)(bn * 192 + r) * 6144 + kt * 64 + sgc,
           &ldsB[buf][(j * 64 + w * 8) * 64]);
  };

  f32x4 acc[8][3];
#pragma unroll
  for (int m = 0; m < 8; ++m)
#pragma unroll
    for (int n = 0; n < 3; ++n)
#pragma unroll
      for (int j = 0; j < 4; ++j) acc[m][n][j] = 0.f;

  // prologue: stage tile 0 into buf 0, drain
  stA(0, 0, 0); stA(0, 0, 1); stA(0, 0, 2); stA(0, 0, 3);
  stB(0, 0, 0); stB(0, 0, 1); stB(0, 0, 2);
  asm volatile("s_waitcnt vmcnt(0)" ::: "memory");
  __builtin_amdgcn_s_barrier();

  const int aRow0 = wr * 128 + lr;
  const int bRow0 = wc * 48 + lr;
  const int c0 = (lg ^ (lr & 7)) * 8;  // swizzled hi-chunk addr; lo = ^32

#define RD_A(MQ)                                                           \
  _Pragma("unroll") for (int m = 0; m < 4; ++m) {                          \
    const int off = (aRow0 + (MQ)*64 + m * 16) * 64 + c0;                  \
    ah[m] = ld16(&LA[off]);                                                \
    al[m] = ld16(&LA[off ^ 32]);                                           \
  }
#define DO_MFMA3(MQ)                                                       \
  __builtin_amdgcn_s_setprio(1);                                           \
  _Pragma("unroll") for (int m = 0; m < 4; ++m)                            \
  _Pragma("unroll") for (int n = 0; n < 3; ++n) {                          \
    acc[(MQ)*4 + m][n] = MFMA(ah[m], bh[n], acc[(MQ)*4 + m][n]);           \
    acc[(MQ)*4 + m][n] = MFMA(ah[m], bl[n], acc[(MQ)*4 + m][n]);           \
    acc[(MQ)*4 + m][n] = MFMA(al[m], bh[n], acc[(MQ)*4 + m][n]);           \
  }                                                                        \
  __builtin_amdgcn_s_setprio(0);
#define PH_SYNC()                                                          \
  __builtin_amdgcn_s_barrier();                                            \
  asm volatile("s_waitcnt lgkmcnt(0)" ::: "memory");                       \
  __builtin_amdgcn_sched_barrier(0);

  for (int t = 0; t < NT; ++t) {
    const int cur = t & 1;
    const int nxt = cur ^ 1;
    const u16* LA = ldsA[cur];
    const u16* LB = ldsB[cur];
    bf16x8 ah[4], al[4], bh[3], bl[3];
    // ph0: B frags + A half 0; stage full tile t+1
#pragma unroll
    for (int n = 0; n < 3; ++n) {
      const int off = (bRow0 + n * 16) * 64 + c0;
      bh[n] = ld16(&LB[off]);
      bl[n] = ld16(&LB[off ^ 32]);
    }
    RD_A(0);
    if (t + 1 < NT) {
      stA(nxt, t + 1, 0); stA(nxt, t + 1, 1);
      stA(nxt, t + 1, 2); stA(nxt, t + 1, 3);
      stB(nxt, t + 1, 0); stB(nxt, t + 1, 1); stB(nxt, t + 1, 2);
    }
    PH_SYNC();
    DO_MFMA3(0);
    __builtin_amdgcn_s_barrier();
    // ph1: A half 1
    RD_A(1);
    PH_SYNC();
    DO_MFMA3(1);
    asm volatile("s_waitcnt vmcnt(0)" ::: "memory");
    __builtin_amdgcn_s_barrier();
  }
#undef RD_A
#undef DO_MFMA3
#undef PH_SYNC

  // epilogue: C/D layout col=lane&15, row=(lane>>4)*4+j (m89-verified)
#pragma unroll
  for (int m = 0; m < 8; ++m)
#pragma unroll
    for (int j = 0; j < 4; ++j) {
      const long row = (long)bm * 256 + wr * 128 + m * 16 + lg * 4 + j;
#pragma unroll
      for (int n = 0; n < 3; ++n) {
        const int col = bn * 192 + wc * 48 + n * 16 + lr;
        const float v = acc[m][n][j];
        if (MODE == 0) {
          const long idx = row * (2L * N) + (col >> 5) * 64 + (col & 31);
          u16 h, l;
          split2(v, h, l);
          C2[idx] = h;
          C2[idx + 32] = l;
        } else {
          Cf[row * N + col] = v + bias[col];
        }
      }
    }
}

// ---------------------------------------------------------------- pack K ---
// K records from interleaved QKV2; Kp format unchanged (attn-compatible).
__global__ void pack_k(const u16* __restrict__ QKV2, u16* __restrict__ Kp) {
  const int t = blockIdx.x * 256 + threadIdx.x;
  const int lane = t & 63;
  const int rec3 = t >> 6;
  const int c = rec3 % 3;
  const int kb = (rec3 / 3) & 127;
  const int hl = rec3 / 384;
  const int lr = lane & 15, lg = lane >> 4;
  const long src = ((long)((hl >> 5) * 2048 + kb * 16 + lr)) * 18432 +
                   (96 + (hl & 31) * 3 + c) * 64 + lg * 8;
  const long dst = ((long)rec3 * 2) * 512 + lane * 8;
  *reinterpret_cast<bf16x8*>(Kp + dst) = ld16(QKV2 + src);
  *reinterpret_cast<bf16x8*>(Kp + dst + 512) = ld16(QKV2 + src + 32);
}

// ---------------------------------------------------------------- pack V ---
__global__ __launch_bounds__(256) void pack_v(const u16* __restrict__ QKV2,
                                              u16* __restrict__ Vp) {
  __shared__ u16 sV[2][32 * 96];
  const int tid = threadIdx.x;
  const int hl = blockIdx.x >> 6;
  const int kq = blockIdx.x & 63;
  const long rowbase = ((long)((hl >> 5) * 2048 + kq * 32)) * 18432 +
                       (192 + (hl & 31) * 3) * 64;
#pragma unroll
  for (int i = 0; i < 3; ++i) {
    const int idx = i * 256 + tid;  // [pl][row(32)][cu(12)]
    const int pl = idx / 384;
    const int r2 = idx % 384;
    const int row = r2 / 12, cu = r2 % 12;
    const long src = rowbase + (long)row * 18432 + (cu >> 2) * 64 + (cu & 3) * 8 + pl * 32;
    *reinterpret_cast<bf16x8*>(&sV[pl][row * 96 + cu * 8]) = ld16(QKV2 + src);
  }
  __syncthreads();
#pragma unroll
  for (int i = 0; i < 3; ++i) {
    const int idx = i * 256 + tid;
    const int lane = idx & 63;
    const int rl = idx >> 6;
    const int n = rl >> 1, pl = rl & 1;
    const int lr = lane & 15, lg = lane >> 4;
    bf16x8 o;
#pragma unroll
    for (int e = 0; e < 8; ++e) o[e] = (short)sV[pl][(lg * 8 + e) * 96 + n * 16 + lr];
    const long dst = ((((long)hl * 6 + n) * 64 + kq) * 2 + pl) * 512 + lane * 8;
    *reinterpret_cast<bf16x8*>(Vp + dst) = o;
  }
}

// ------------------------------------------------------------- attention ---
__global__ __launch_bounds__(256, 2) void attn_kernel(
    const u16* __restrict__ QKV2,
    const u16* __restrict__ Kp, const u16* __restrict__ Vp,
    u16* __restrict__ AO2) {
  __shared__ u16 kv[2][24 * 512];
  __shared__ u16 pb[4][2][512];
  const int lane = threadIdx.x & 63;
  const int wv = threadIdx.x >> 6;
  const int lr = lane & 15, lg = lane >> 4;

  const int nwg = gridDim.x;
  const int bid = blockIdx.x;
  const int wg = (bid & 7) * (nwg >> 3) + (bid >> 3);
  const int hl = wg >> 5;
  const int qblk = wg & 31;
  const int b = hl >> 5;
  const int q0 = qblk * 64 + wv * 16;

  bf16x8 qh[3], ql[3];
  {
    const long qofs =
        ((long)(b * 2048 + q0 + lr)) * 18432 + ((hl & 31) * 3) * 64 + lg * 8;
#pragma unroll
    for (int c = 0; c < 3; ++c) {
      qh[c] = ld16(QKV2 + qofs + c * 64);
      ql[c] = ld16(QKV2 + qofs + c * 64 + 32);
    }
  }

  f32x4 o_acc[6];
#pragma unroll
  for (int n = 0; n < 6; ++n)
#pragma unroll
    for (int j = 0; j < 4; ++j) o_acc[n][j] = 0.f;
  float lsum[4] = {0.f, 0.f, 0.f, 0.f};

  const float scale = 0.10206207261596577f;  // 96^-0.5
  u16* pbh = pb[wv][0];
  u16* pbl = pb[wv][1];

  auto stage = [&](int nb, int it) {
    const long kbase = ((long)hl * 768 + (long)it * 12) * 512;
    const long vbase = ((long)hl * 768 + (long)it * 2) * 512;
#pragma unroll
    for (int j = 0; j < 6; ++j) {
      const int r = wv * 6 + j;
      const u16* src;
      if (r < 12) {
        const int tt = r / 6, rc = r % 6;
        src = Kp + kbase + ((long)(tt * 6 + rc)) * 512 + lane * 8;
      } else {
        const int r2 = r - 12;
        src = Vp + vbase + ((long)((r2 >> 1) * 128 + (r2 & 1))) * 512 + lane * 8;
      }
      GLDS16(src, &kv[nb][r * 512]);
    }
  };

  stage(0, 0);
  __syncthreads();

  for (int it = 0; it < 64; ++it) {
    const int nb = it & 1;
    if (it < 63) stage(nb ^ 1, it + 1);
    const u16* L = kv[nb];

    f32x4 s0, s1;
#pragma unroll
    for (int j = 0; j < 4; ++j) { s0[j] = 0.f; s1[j] = 0.f; }
#pragma unroll
    for (int c = 0; c < 3; ++c) {
      const bf16x8 kh0 = ld16(L + (c * 2 + 0) * 512 + lane * 8);
      const bf16x8 kl0 = ld16(L + (c * 2 + 1) * 512 + lane * 8);
      const bf16x8 kh1 = ld16(L + (6 + c * 2 + 0) * 512 + lane * 8);
      const bf16x8 kl1 = ld16(L + (6 + c * 2 + 1) * 512 + lane * 8);
      s0 = MFMA(qh[c], kh0, s0);
      s1 = MFMA(qh[c], kh1, s1);
      s0 = MFMA(qh[c], kl0, s0);
      s1 = MFMA(qh[c], kl1, s1);
      s0 = MFMA(ql[c], kh0, s0);
      s1 = MFMA(ql[c], kh1, s1);
    }

#pragma unroll
    for (int j = 0; j < 4; ++j) {
      const float p0 = __expf(fmaf(s0[j], scale, -12.f));
      const float p1 = __expf(fmaf(s1[j], scale, -12.f));
      lsum[j] += p0 + p1;
      const int r = lg * 4 + j;
      const int key = j ^ lg;
      u16 h, l;
      split2(p0, h, l);
      const int a0 = r * 32 + ((((lr >> 3) ^ key) & 3) << 3) + (lr & 7);
      pbh[a0] = h;
      pbl[a0] = l;
      split2(p1, h, l);
      const int a1 = r * 32 + ((((2 + (lr >> 3)) ^ key) & 3) << 3) + (lr & 7);
      pbh[a1] = h;
      pbl[a1] = l;
    }
    const int rkey = (lr & 3) ^ (lr >> 2);
    const int ra = lr * 32 + (((lg ^ rkey) & 3) << 3);
    const bf16x8 pah = ld16(&pbh[ra]);
    const bf16x8 pal = ld16(&pbl[ra]);

#pragma unroll
    for (int n = 0; n < 6; ++n) {
      const bf16x8 vh = ld16(L + (12 + n * 2 + 0) * 512 + lane * 8);
      const bf16x8 vl = ld16(L + (12 + n * 2 + 1) * 512 + lane * 8);
      o_acc[n] = MFMA(pah, vh, o_acc[n]);
      o_acc[n] = MFMA(pah, vl, o_acc[n]);
      o_acc[n] = MFMA(pal, vh, o_acc[n]);
    }
    __syncthreads();
  }

  float inv[4];
#pragma unroll
  for (int j = 0; j < 4; ++j) {
    float rs = lsum[j];
#pragma unroll
    for (int mk = 1; mk < 16; mk <<= 1) rs += __shfl_xor(rs, mk);
    inv[j] = 1.f / rs;
  }
#pragma unroll
  for (int n = 0; n < 6; ++n)
#pragma unroll
    for (int j = 0; j < 4; ++j) {
      const long row = (long)(b * 2048 + q0 + lg * 4 + j);
      const long idx =
          row * 6144 + ((hl & 31) * 3 + (n >> 1)) * 64 + (n & 1) * 16 + lr;
      u16 h, l;
      split2(o_acc[n][j] * inv[j], h, l);
      AO2[idx] = h;
      AO2[idx + 32] = l;
    }
}

// ---------------------------------------------------------------- launch ---
extern "C" void kernel_launch(void* const* d_in, const int* in_sizes, int n_in,
                              void* d_out, int out_size, void* d_ws, size_t ws_size,
                              hipStream_t stream) {
  const float* x = (const float*)d_in[0];     // [4096][3072]
  const float* wqkv = (const float*)d_in[1];  // [9216][3072]
  const float* wo = (const float*)d_in[2];    // [3072][3072]
  const float* bo = (const float*)d_in[3];    // [3072]
  float* out = (float*)d_out;                 // [4096][3072]
  char* ws = (char*)d_ws;

  const size_t E_X = (size_t)4096 * 3072;
  const size_t E_WQ = (size_t)9216 * 3072;
  const size_t E_QKV = (size_t)4096 * 9216;
  const size_t E_WO = (size_t)3072 * 3072;

  // layout (bytes): X2[4E_X] | W2[4E_WQ] | QKV2[4E_QKV] | VP[4E_X]
  u16* X2 = (u16*)ws;
  char* W0 = ws + 4 * E_X;
  u16* W2 = (u16*)W0;
  char* Q0 = W0 + 4 * E_WQ;
  u16* QKV2 = (u16*)Q0;
  char* V0 = Q0 + 4 * E_QKV;
  u16* VP = (u16*)V0;
  u16* KP = (u16*)ws;              // reuses X2 region after GEMM1 (exact fit)
  u16* AO2 = (u16*)W0;             // reuses W2 region after GEMM1
  u16* WO2 = (u16*)(W0 + 4 * E_X);

  const size_t need = 4 * (E_X + E_WQ + E_QKV + E_X);
  if (ws_size < need) return;

  split_kernel<<<12288, 256, 0, stream>>>(x, X2, (long)E_X);
  split_kernel<<<27648, 256, 0, stream>>>(wqkv, W2, (long)E_WQ);
  gemm3t<0><<<768, 512, 0, stream>>>(X2, W2, 4096, 9216, QKV2, nullptr, nullptr);
  pack_k<<<6144, 256, 0, stream>>>(QKV2, KP);
  pack_v<<<4096, 256, 0, stream>>>(QKV2, VP);
  split_kernel<<<9216, 256, 0, stream>>>(wo, WO2, (long)E_WO);
  attn_kernel<<<2048, 256, 0, stream>>>(QKV2, KP, VP, AO2);
  gemm3t<1><<<256, 512, 0, stream>>>(AO2, WO2, 4096, 3072, nullptr, out, bo);
}